// Round 9
// baseline (263.525 us; speedup 1.0000x reference)
//
#include <hip/hip_runtime.h>

typedef __bf16 bf16x8 __attribute__((ext_vector_type(8)));
typedef float f32x4 __attribute__((ext_vector_type(4)));
typedef unsigned short u16;
typedef u16 u16x8 __attribute__((ext_vector_type(8)));

#define AS1 __attribute__((address_space(1)))
#define AS3 __attribute__((address_space(3)))
#define MF(d, a, b) d = __builtin_amdgcn_mfma_f32_16x16x32_bf16(a, b, d, 0, 0, 0)

// split fp32 -> bf16 hi + bf16 lo (x ~= hi + lo, error ~2^-17 relative)
__device__ __forceinline__ void split2(float x, u16& h, u16& l) {
  __bf16 hb = (__bf16)x;
  float hf = (float)hb;
  __bf16 lb = (__bf16)(x - hf);
  h = __builtin_bit_cast(u16, hb);
  l = __builtin_bit_cast(u16, lb);
}

// ---- prep: Ws [4096][2048] f32 -> packed [4096][64 kb][hi 32 | lo 32] bf16
__global__ __launch_bounds__(256) void k_pack_ws(const float* __restrict__ X,
                                                 u16* __restrict__ P) {
  const int total8 = (4096 * 2048) / 8;
  for (int idx = blockIdx.x * 256 + threadIdx.x; idx < total8; idx += gridDim.x * 256) {
    int row = idx >> 8;
    int k8  = idx & 255;
    const float* src = X + ((size_t)row << 11) + (k8 << 3);
    const float4 v0 = *(const float4*)src;
    const float4 v1 = *(const float4*)(src + 4);
    float xv[8] = {v0.x, v0.y, v0.z, v0.w, v1.x, v1.y, v1.z, v1.w};
    u16x8 hv, lv;
#pragma unroll
    for (int j = 0; j < 8; ++j) { u16 h, l; split2(xv[j], h, l); hv[j] = h; lv[j] = l; }
    size_t base = ((size_t)row << 12) + (size_t)((k8 >> 2) << 6) + ((k8 & 3) << 3);
    *(u16x8*)(P + base) = hv;
    *(u16x8*)(P + base + 32) = lv;
  }
}

// ---- prep: W [2048][2048] f32 -> WT packed [2048][64][64], WT[c][k] = W[k][c]
__global__ __launch_bounds__(256) void k_transpose_pack_w(const float* __restrict__ W,
                                                          u16* __restrict__ P) {
  __shared__ float tile[32][33];
  const int tx = threadIdx.x, ty = threadIdx.y;  // 32 x 8
  const int kbase = blockIdx.y << 5, cbase = blockIdx.x << 5;
#pragma unroll
  for (int i = 0; i < 4; ++i)
    tile[ty * 4 + i][tx] = W[((size_t)(kbase + ty * 4 + i) << 11) + cbase + tx];
  __syncthreads();
#pragma unroll
  for (int i = 0; i < 4; ++i) {
    int c = cbase + ty * 4 + i;
    float v = tile[tx][ty * 4 + i];
    u16 h, l; split2(v, h, l);
    size_t base = ((size_t)c << 12) + (size_t)(kbase << 1) + tx;
    P[base] = h;
    P[base + 32] = l;
  }
}

// ---- GEMM1: NT 128x128 tile m97-structure, 16x16x32 + XCD swizzle (proven)
__global__ __launch_bounds__(256, 2) void k_gemm_nt(const u16* __restrict__ Ap,
                                                    const u16* __restrict__ Bp,
                                                    u16* __restrict__ Cpack) {
  __shared__ __align__(16) u16 lds_a[128 * 64];
  __shared__ __align__(16) u16 lds_b[128 * 64];
  const int bid = blockIdx.x;
  const int swzb = (bid & 7) * 64 + (bid >> 3);   // 512 blocks, 64 per XCD
  const int bx = swzb & 15, by = swzb >> 4;
  const int tid = threadIdx.x;
  const int lane = tid & 63, w = tid >> 6;
  const int wr = w >> 1, wc = w & 1;
  const int row0 = by << 7, col0 = bx << 7;
  const int lrow = lane & 15, kg = lane >> 4;

  f32x4 acc[4][4] = {};

  const u16* abase = Ap + ((size_t)row0 << 12);
  const u16* bbase = Bp + ((size_t)col0 << 12);

  int offAh[4], offAl[4], offBh[4], offBl[4];
#pragma unroll
  for (int m = 0; m < 4; ++m) {
    int r = wr * 64 + m * 16 + lrow;
    int sw = r & 7;
    offAh[m] = r * 64 + ((kg ^ sw) << 3);
    offAl[m] = r * 64 + (((4 + kg) ^ sw) << 3);
    int rb = wc * 64 + m * 16 + lrow;
    int swb = rb & 7;
    offBh[m] = rb * 64 + ((kg ^ swb) << 3);
    offBl[m] = rb * 64 + (((4 + kg) ^ swb) << 3);
  }

  for (int kb = 0; kb < 64; ++kb) {
    const int kofs = kb << 6;
#pragma unroll
    for (int i = 0; i < 4; ++i) {
      int s = i * 256 + tid;
      int r = s >> 3, c = s & 7;
      int cs = c ^ (r & 7);
      __builtin_amdgcn_global_load_lds(
          (const AS1 unsigned int*)(abase + ((size_t)r << 12) + kofs + (cs << 3)),
          (AS3 unsigned int*)(lds_a + ((i * 256 + w * 64) << 3)), 16, 0, 0);
    }
#pragma unroll
    for (int i = 0; i < 4; ++i) {
      int s = i * 256 + tid;
      int r = s >> 3, c = s & 7;
      int cs = c ^ (r & 7);
      __builtin_amdgcn_global_load_lds(
          (const AS1 unsigned int*)(bbase + ((size_t)r << 12) + kofs + (cs << 3)),
          (AS3 unsigned int*)(lds_b + ((i * 256 + w * 64) << 3)), 16, 0, 0);
    }
    __syncthreads();

    bf16x8 ah[4], al[4];
#pragma unroll
    for (int m = 0; m < 4; ++m) {
      ah[m] = *(const bf16x8*)&lds_a[offAh[m]];
      al[m] = *(const bf16x8*)&lds_a[offAl[m]];
    }
#pragma unroll
    for (int n = 0; n < 4; ++n) {
      bf16x8 bh = *(const bf16x8*)&lds_b[offBh[n]];
      bf16x8 bl = *(const bf16x8*)&lds_b[offBl[n]];
#pragma unroll
      for (int m = 0; m < 4; ++m) {
        MF(acc[m][n], ah[m], bh);
        MF(acc[m][n], ah[m], bl);
        MF(acc[m][n], al[m], bh);
      }
    }
    __syncthreads();
  }

#pragma unroll
  for (int m = 0; m < 4; ++m) {
#pragma unroll
    for (int n = 0; n < 4; ++n) {
#pragma unroll
      for (int j = 0; j < 4; ++j) {
        int gr = row0 + wr * 64 + m * 16 + kg * 4 + j;
        int gc = col0 + wc * 64 + n * 16 + lrow;
        u16 h, l; split2(acc[m][n][j], h, l);
        size_t base = ((size_t)gr << 12) + (size_t)((gc >> 5) << 6) + (gc & 31);
        Cpack[base] = h;
        Cpack[base + 32] = l;
      }
    }
  }
}

// ---- GEMM2: 256x256 8-phase + balanced cross-tile B-register prefetch.
// B regs: set E (even tiles), set O (odd tiles). t0 always even -> buffers
// fully static: A(t0)=sm, A(t1)=sm+16384, B(t0)=sm+32768, B(t1)=sm+49152.
// Per phase reads: 4 A-frags + {0,3,3,2} B-prefetch (next tile) = max 7
// (vs old q0 burst of 12). Stage ledger unchanged:
//   p0: A(T1)j1,j3 | p1: B(T2)j0,j1 | p2: B(T2)j2,j3 | p3: A(T2)j0,j2
//   p4: A(T2)j1,j3 | p5: B(T3)j0,j1 | p6: B(T3)j2,j3 | p7: A(T3)j0,j2
// Wait ledger (invariant: 6 in flight at iter boundary = B(T1)x4 + A(T1)j0,j2):
//   p0: vmcnt(4)  retires prev p5,p6 = B(t0+1)   -> O-prefetch at p1-p3 safe
//   p3: vmcnt(6)  retires prev p7,p0 = A(t0+1)   -> p4-p7 A reads safe
//   p4: vmcnt(4)  retires p1,p2     = B(t0+2)    -> E-prefetch at p5-p7 safe
//   p7: vmcnt(6)  retires p3,p4     = A(t0+2)    -> next-iter A reads safe
// All waits target loads >=2-4 phases (~580+ cyc) old vs L2 ~200-300 -> ~free.
__global__ __launch_bounds__(512, 2) void k_gemm256(const u16* __restrict__ Ap,
                                                    const u16* __restrict__ Bp,
                                                    float* __restrict__ Cout) {
  __shared__ __align__(16) u16 sm[65536];  // A0|A1|B0|B1, 32KB each = 128KiB
  const int bid = blockIdx.x;
  const int swzb = (bid & 7) * 32 + (bid >> 3);  // 256 blocks, 32 per XCD
  const int bx = swzb & 15, by = swzb >> 4;
  const int tid = threadIdx.x;
  const int lane = tid & 63, w = tid >> 6;
  const int wr = w >> 2, wc = w & 3;           // 2x4 waves, per-wave 128x64 out
  const int row0 = by << 8, col0 = bx << 8;
  const int lrow = lane & 15, kg = lane >> 4;
  const int sw = lrow & 7;

  const u16* Abase = Ap + ((size_t)row0 << 12);  // pack row stride 4096 u16
  const u16* Bbase = Bp + ((size_t)col0 << 12);

  const size_t gsrc0 = ((size_t)(tid >> 3) << 12) + ((size_t)((tid & 7) ^ ((tid >> 3) & 7)) << 3);
  const int dst0 = (w * 64) << 3;

  auto stA = [&](int T, int j) {
    __builtin_amdgcn_global_load_lds(
        (const AS1 unsigned int*)(Abase + gsrc0 + ((size_t)(j * 64) << 12) + ((T & 63) << 6)),
        (AS3 unsigned int*)(sm + ((T & 1) << 14) + j * 4096 + dst0), 16, 0, 0);
  };
  auto stB = [&](int T, int j) {
    __builtin_amdgcn_global_load_lds(
        (const AS1 unsigned int*)(Bbase + gsrc0 + ((size_t)(j * 64) << 12) + ((T & 63) << 6)),
        (AS3 unsigned int*)(sm + 32768 + ((T & 1) << 14) + j * 4096 + dst0), 16, 0, 0);
  };

  const int baseAh = (wr * 128 + lrow) * 64 + ((kg ^ sw) << 3);
  const int baseAl = (wr * 128 + lrow) * 64 + (((4 | kg) ^ sw) << 3);
  const int baseBh = (wc * 64 + lrow) * 64 + ((kg ^ sw) << 3);
  const int baseBl = (wc * 64 + lrow) * 64 + (((4 | kg) ^ sw) << 3);

  const u16* laE = sm;            // A(t0), t0 even
  const u16* laO = sm + 16384;    // A(t1)
  const u16* lbE = sm + 32768;    // B(t0)
  const u16* lbO = sm + 49152;    // B(t1)

  f32x4 acc[8][4] = {};
  bf16x8 bhE[4], blE[4], bhO[4], blO[4];

  // prologue: T0 full (8), B(T1) j0-3, A(T1) j0,j2 -> vmcnt(6) = T0 landed
  stA(0, 0); stA(0, 1); stA(0, 2); stA(0, 3);
  stB(0, 0); stB(0, 1); stB(0, 2); stB(0, 3);
  stB(1, 0); stB(1, 1); stB(1, 2); stB(1, 3);
  stA(1, 0); stA(1, 2);
  asm volatile("s_waitcnt vmcnt(6)" ::: "memory");
  __builtin_amdgcn_sched_barrier(0);
  __builtin_amdgcn_s_barrier();
  // fill B(0) regs (one-time burst; B(0) landed by prologue vmcnt)
#pragma unroll
  for (int n = 0; n < 4; ++n) {
    bhE[n] = *(const bf16x8*)&lbE[baseBh + n * 1024];
    blE[n] = *(const bf16x8*)&lbE[baseBl + n * 1024];
  }

  for (int i = 0; i < 32; ++i) {
    const int t0 = 2 * i;
#pragma unroll
    for (int p = 0; p < 8; ++p) {
      const int q = p & 3;
      const u16* la = (p < 4) ? laE : laO;
      // A-frags for this phase (issue first so MFMA's lgkm wait covers A only)
      bf16x8 ah0 = *(const bf16x8*)&la[baseAh + (2 * q) * 1024];
      bf16x8 al0 = *(const bf16x8*)&la[baseAl + (2 * q) * 1024];
      bf16x8 ah1 = *(const bf16x8*)&la[baseAh + (2 * q + 1) * 1024];
      bf16x8 al1 = *(const bf16x8*)&la[baseAl + (2 * q + 1) * 1024];
      // cross-tile B prefetch (next tile's frags, 0-3 reads/phase)
      switch (p) {
        case 1: bhO[0] = *(const bf16x8*)&lbO[baseBh];
                blO[0] = *(const bf16x8*)&lbO[baseBl];
                bhO[1] = *(const bf16x8*)&lbO[baseBh + 1024]; break;
        case 2: blO[1] = *(const bf16x8*)&lbO[baseBl + 1024];
                bhO[2] = *(const bf16x8*)&lbO[baseBh + 2048];
                blO[2] = *(const bf16x8*)&lbO[baseBl + 2048]; break;
        case 3: bhO[3] = *(const bf16x8*)&lbO[baseBh + 3072];
                blO[3] = *(const bf16x8*)&lbO[baseBl + 3072]; break;
        case 5: bhE[0] = *(const bf16x8*)&lbE[baseBh];
                blE[0] = *(const bf16x8*)&lbE[baseBl];
                bhE[1] = *(const bf16x8*)&lbE[baseBh + 1024]; break;
        case 6: blE[1] = *(const bf16x8*)&lbE[baseBl + 1024];
                bhE[2] = *(const bf16x8*)&lbE[baseBh + 2048];
                blE[2] = *(const bf16x8*)&lbE[baseBl + 2048]; break;
        case 7: bhE[3] = *(const bf16x8*)&lbE[baseBh + 3072];
                blE[3] = *(const bf16x8*)&lbE[baseBl + 3072]; break;
        default: break;
      }
      // staging (ledger unchanged)
      switch (p) {
        case 0: stA(t0 + 1, 1); stA(t0 + 1, 3); break;
        case 1: stB(t0 + 2, 0); stB(t0 + 2, 1); break;
        case 2: stB(t0 + 2, 2); stB(t0 + 2, 3); break;
        case 3: stA(t0 + 2, 0); stA(t0 + 2, 2); break;
        case 4: stA(t0 + 2, 1); stA(t0 + 2, 3); break;
        case 5: stB(t0 + 3, 0); stB(t0 + 3, 1); break;
        case 6: stB(t0 + 3, 2); stB(t0 + 3, 3); break;
        case 7: stA(t0 + 3, 0); stA(t0 + 3, 2); break;
      }
      __builtin_amdgcn_s_barrier();
      __builtin_amdgcn_s_setprio(1);
      const int m0 = 2 * q, m1 = 2 * q + 1;
      if (p < 4) {
#pragma unroll
        for (int n = 0; n < 4; ++n) { MF(acc[m0][n], ah0, bhE[n]); MF(acc[m1][n], ah1, bhE[n]); }
#pragma unroll
        for (int n = 0; n < 4; ++n) { MF(acc[m0][n], ah0, blE[n]); MF(acc[m1][n], ah1, blE[n]); }
#pragma unroll
        for (int n = 0; n < 4; ++n) { MF(acc[m0][n], al0, bhE[n]); MF(acc[m1][n], al1, bhE[n]); }
      } else {
#pragma unroll
        for (int n = 0; n < 4; ++n) { MF(acc[m0][n], ah0, bhO[n]); MF(acc[m1][n], ah1, bhO[n]); }
#pragma unroll
        for (int n = 0; n < 4; ++n) { MF(acc[m0][n], ah0, blO[n]); MF(acc[m1][n], ah1, blO[n]); }
#pragma unroll
        for (int n = 0; n < 4; ++n) { MF(acc[m0][n], al0, bhO[n]); MF(acc[m1][n], al1, bhO[n]); }
      }
      __builtin_amdgcn_s_setprio(0);
      asm volatile("s_waitcnt lgkmcnt(0)" ::: "memory");
      __builtin_amdgcn_sched_barrier(0);
      if (p == 0 || p == 4) {
        asm volatile("s_waitcnt vmcnt(4)" ::: "memory");
        __builtin_amdgcn_sched_barrier(0);
      }
      if (p == 3 || p == 7) {
        asm volatile("s_waitcnt vmcnt(6)" ::: "memory");
        __builtin_amdgcn_sched_barrier(0);
      }
      __builtin_amdgcn_s_barrier();
    }
  }
  asm volatile("s_waitcnt vmcnt(0)" ::: "memory");

  // epilogue: C frag col=lane&15, row=kg*4+j
#pragma unroll
  for (int m = 0; m < 8; ++m) {
#pragma unroll
    for (int n = 0; n < 4; ++n) {
#pragma unroll
      for (int j = 0; j < 4; ++j) {
        int gr = row0 + wr * 128 + m * 16 + kg * 4 + j;
        int gc = col0 + wc * 64 + n * 16 + lrow;
        Cout[((size_t)gr << 12) + gc] = acc[m][n][j];
      }
    }
  }
}

// ---- row softmax in place over [4096][4096] f32
__global__ __launch_bounds__(256) void k_softmax_rows(float* __restrict__ A) {
  const int row = blockIdx.x;
  float* p = A + ((size_t)row << 12);
  const int tid = threadIdx.x;
  const int lane = tid & 63, w = tid >> 6;
  float4 v[4];
  float mx = -3.0e38f;
#pragma unroll
  for (int i = 0; i < 4; ++i) {
    v[i] = ((const float4*)p)[tid + (i << 8)];
    mx = fmaxf(mx, fmaxf(fmaxf(v[i].x, v[i].y), fmaxf(v[i].z, v[i].w)));
  }
#pragma unroll
  for (int off = 32; off; off >>= 1) mx = fmaxf(mx, __shfl_xor(mx, off, 64));
  __shared__ float redm[4], reds[4];
  if (lane == 0) redm[w] = mx;
  __syncthreads();
  mx = fmaxf(fmaxf(redm[0], redm[1]), fmaxf(redm[2], redm[3]));
  float s = 0.f;
#pragma unroll
  for (int i = 0; i < 4; ++i) {
    v[i].x = __expf(v[i].x - mx);
    v[i].y = __expf(v[i].y - mx);
    v[i].z = __expf(v[i].z - mx);
    v[i].w = __expf(v[i].w - mx);
    s += (v[i].x + v[i].y) + (v[i].z + v[i].w);
  }
#pragma unroll
  for (int off = 32; off; off >>= 1) s += __shfl_xor(s, off, 64);
  if (lane == 0) reds[w] = s;
  __syncthreads();
  s = (reds[0] + reds[1]) + (reds[2] + reds[3]);
  const float inv = 1.0f / s;
#pragma unroll
  for (int i = 0; i < 4; ++i) {
    v[i].x *= inv; v[i].y *= inv; v[i].z *= inv; v[i].w *= inv;
    ((float4*)p)[tid + (i << 8)] = v[i];
  }
}

extern "C" void kernel_launch(void* const* d_in, const int* in_sizes, int n_in,
                              void* d_out, int out_size, void* d_ws, size_t ws_size,
                              hipStream_t stream) {
  (void)in_sizes; (void)n_in; (void)out_size; (void)ws_size;
  const float* Ws = (const float*)d_in[0];   // [4096][2048] f32
  const float* W  = (const float*)d_in[1];   // [1][2048][2048] f32
  // d_in[2] = bias[1]: constant across each row -> softmax-invariant, skipped.
  float* out = (float*)d_out;                // [4096][4096] f32

  u16* ws_pack = (u16*)d_ws;                       // [4096][4096] u16
  u16* wt_pack = ws_pack + (size_t)4096 * 4096;    // [2048][4096] u16
  u16* t_pack  = wt_pack + (size_t)2048 * 4096;    // [4096][4096] u16

  k_pack_ws<<<4096, 256, 0, stream>>>(Ws, ws_pack);
  k_transpose_pack_w<<<dim3(64, 64), dim3(32, 8), 0, stream>>>(W, wt_pack);
  // t = Ws @ W  (NT), split-epilogue back into packed hi/lo
  k_gemm_nt<<<512, 256, 0, stream>>>(ws_pack, wt_pack, t_pack);
  // A = t @ Ws^T (NT), 8-phase 256^2 + balanced B-prefetch, fp32 logits
  k_gemm256<<<256, 512, 0, stream>>>(t_pack, ws_pack, out);
  k_softmax_rows<<<4096, 256, 0, stream>>>(out);
}

// Round 10
// 259.648 us; speedup vs baseline: 1.0149x; 1.0149x over previous
//
#include <hip/hip_runtime.h>

typedef __bf16 bf16x8 __attribute__((ext_vector_type(8)));
typedef float f32x4 __attribute__((ext_vector_type(4)));
typedef unsigned short u16;
typedef u16 u16x8 __attribute__((ext_vector_type(8)));

#define AS1 __attribute__((address_space(1)))
#define AS3 __attribute__((address_space(3)))
#define MF(d, a, b) d = __builtin_amdgcn_mfma_f32_16x16x32_bf16(a, b, d, 0, 0, 0)

// split fp32 -> bf16 hi + bf16 lo (x ~= hi + lo, error ~2^-17 relative)
__device__ __forceinline__ void split2(float x, u16& h, u16& l) {
  __bf16 hb = (__bf16)x;
  float hf = (float)hb;
  __bf16 lb = (__bf16)(x - hf);
  h = __builtin_bit_cast(u16, hb);
  l = __builtin_bit_cast(u16, lb);
}

// ---- fused prep (one launch):
// blocks [0,4096):    Ws [4096][2048] f32 -> packed [4096][64 kb][hi32|lo32]
// blocks [4096,8192): W [2048][2048] f32 -> WT packed [2048][64][64] (transposed)
__global__ __launch_bounds__(256) void k_prep(const float* __restrict__ Ws,
                                              u16* __restrict__ Pws,
                                              const float* __restrict__ W,
                                              u16* __restrict__ Pwt) {
  __shared__ float tile[32][33];
  const int bid = blockIdx.x;
  const int tid = threadIdx.x;
  if (bid < 4096) {
    int idx = bid * 256 + tid;            // covers 4096*2048/8 exactly
    int row = idx >> 8;
    int k8  = idx & 255;
    const float* src = Ws + ((size_t)row << 11) + (k8 << 3);
    const float4 v0 = *(const float4*)src;
    const float4 v1 = *(const float4*)(src + 4);
    float xv[8] = {v0.x, v0.y, v0.z, v0.w, v1.x, v1.y, v1.z, v1.w};
    u16x8 hv, lv;
#pragma unroll
    for (int j = 0; j < 8; ++j) { u16 h, l; split2(xv[j], h, l); hv[j] = h; lv[j] = l; }
    size_t base = ((size_t)row << 12) + (size_t)((k8 >> 2) << 6) + ((k8 & 3) << 3);
    *(u16x8*)(Pws + base) = hv;
    *(u16x8*)(Pws + base + 32) = lv;
  } else {
    const int b = bid - 4096;
    const int cbase = (b & 63) << 5, kbase = (b >> 6) << 5;
    const int tx = tid & 31, ty = tid >> 5;  // 32 x 8
#pragma unroll
    for (int i = 0; i < 4; ++i)
      tile[ty * 4 + i][tx] = W[((size_t)(kbase + ty * 4 + i) << 11) + cbase + tx];
    __syncthreads();
#pragma unroll
    for (int i = 0; i < 4; ++i) {
      int c = cbase + ty * 4 + i;
      float v = tile[tx][ty * 4 + i];
      u16 h, l; split2(v, h, l);
      size_t base = ((size_t)c << 12) + (size_t)(kbase << 1) + tx;
      Pwt[base] = h;
      Pwt[base + 32] = l;
    }
  }
}

// ---- GEMM1: NT 128x128 tile m97-structure, 16x16x32 + XCD swizzle (proven)
__global__ __launch_bounds__(256, 2) void k_gemm_nt(const u16* __restrict__ Ap,
                                                    const u16* __restrict__ Bp,
                                                    u16* __restrict__ Cpack) {
  __shared__ __align__(16) u16 lds_a[128 * 64];
  __shared__ __align__(16) u16 lds_b[128 * 64];
  const int bid = blockIdx.x;
  const int swzb = (bid & 7) * 64 + (bid >> 3);   // 512 blocks, 64 per XCD
  const int bx = swzb & 15, by = swzb >> 4;
  const int tid = threadIdx.x;
  const int lane = tid & 63, w = tid >> 6;
  const int wr = w >> 1, wc = w & 1;
  const int row0 = by << 7, col0 = bx << 7;
  const int lrow = lane & 15, kg = lane >> 4;

  f32x4 acc[4][4] = {};

  const u16* abase = Ap + ((size_t)row0 << 12);
  const u16* bbase = Bp + ((size_t)col0 << 12);

  int offAh[4], offAl[4], offBh[4], offBl[4];
#pragma unroll
  for (int m = 0; m < 4; ++m) {
    int r = wr * 64 + m * 16 + lrow;
    int sw = r & 7;
    offAh[m] = r * 64 + ((kg ^ sw) << 3);
    offAl[m] = r * 64 + (((4 + kg) ^ sw) << 3);
    int rb = wc * 64 + m * 16 + lrow;
    int swb = rb & 7;
    offBh[m] = rb * 64 + ((kg ^ swb) << 3);
    offBl[m] = rb * 64 + (((4 + kg) ^ swb) << 3);
  }

  for (int kb = 0; kb < 64; ++kb) {
    const int kofs = kb << 6;
#pragma unroll
    for (int i = 0; i < 4; ++i) {
      int s = i * 256 + tid;
      int r = s >> 3, c = s & 7;
      int cs = c ^ (r & 7);
      __builtin_amdgcn_global_load_lds(
          (const AS1 unsigned int*)(abase + ((size_t)r << 12) + kofs + (cs << 3)),
          (AS3 unsigned int*)(lds_a + ((i * 256 + w * 64) << 3)), 16, 0, 0);
    }
#pragma unroll
    for (int i = 0; i < 4; ++i) {
      int s = i * 256 + tid;
      int r = s >> 3, c = s & 7;
      int cs = c ^ (r & 7);
      __builtin_amdgcn_global_load_lds(
          (const AS1 unsigned int*)(bbase + ((size_t)r << 12) + kofs + (cs << 3)),
          (AS3 unsigned int*)(lds_b + ((i * 256 + w * 64) << 3)), 16, 0, 0);
    }
    __syncthreads();

    bf16x8 ah[4], al[4];
#pragma unroll
    for (int m = 0; m < 4; ++m) {
      ah[m] = *(const bf16x8*)&lds_a[offAh[m]];
      al[m] = *(const bf16x8*)&lds_a[offAl[m]];
    }
#pragma unroll
    for (int n = 0; n < 4; ++n) {
      bf16x8 bh = *(const bf16x8*)&lds_b[offBh[n]];
      bf16x8 bl = *(const bf16x8*)&lds_b[offBl[n]];
#pragma unroll
      for (int m = 0; m < 4; ++m) {
        MF(acc[m][n], ah[m], bh);
        MF(acc[m][n], ah[m], bl);
        MF(acc[m][n], al[m], bh);
      }
    }
    __syncthreads();
  }

#pragma unroll
  for (int m = 0; m < 4; ++m) {
#pragma unroll
    for (int n = 0; n < 4; ++n) {
#pragma unroll
      for (int j = 0; j < 4; ++j) {
        int gr = row0 + wr * 64 + m * 16 + kg * 4 + j;
        int gc = col0 + wc * 64 + n * 16 + lrow;
        u16 h, l; split2(acc[m][n][j], h, l);
        size_t base = ((size_t)gr << 12) + (size_t)((gc >> 5) << 6) + (gc & 31);
        Cpack[base] = h;
        Cpack[base + 32] = l;
      }
    }
  }
}

// ---- GEMM2: round-8 exact (best measured: 159.3us, MfmaUtil 57, conflicts 0).
// 256x256, 8 waves, 8-phase, counted vmcnt(6) at p3/p7, XCD-swizzled grid.
//   p0: A(T1)j1,j3 | p1: B(T2)j0,j1 | p2: B(T2)j2,j3 | p3: A(T2)j0,j2
//   p4: A(T2)j1,j3 | p5: B(T3)j0,j1 | p6: B(T3)j2,j3 | p7: A(T3)j0,j2
__global__ __launch_bounds__(512, 2) void k_gemm256(const u16* __restrict__ Ap,
                                                    const u16* __restrict__ Bp,
                                                    float* __restrict__ Cout) {
  __shared__ __align__(16) u16 sm[65536];  // A0|A1|B0|B1, 32KB each = 128KiB
  const int bid = blockIdx.x;
  const int swzb = (bid & 7) * 32 + (bid >> 3);  // 256 blocks, 32 per XCD
  const int bx = swzb & 15, by = swzb >> 4;
  const int tid = threadIdx.x;
  const int lane = tid & 63, w = tid >> 6;
  const int wr = w >> 2, wc = w & 3;           // 2x4 waves, per-wave 128x64 out
  const int row0 = by << 8, col0 = bx << 8;
  const int lrow = lane & 15, kg = lane >> 4;
  const int sw = lrow & 7;

  const u16* Abase = Ap + ((size_t)row0 << 12);  // pack row stride 4096 u16
  const u16* Bbase = Bp + ((size_t)col0 << 12);

  const size_t gsrc0 = ((size_t)(tid >> 3) << 12) + ((size_t)((tid & 7) ^ ((tid >> 3) & 7)) << 3);
  const int dst0 = (w * 64) << 3;

  auto stA = [&](int T, int j) {
    __builtin_amdgcn_global_load_lds(
        (const AS1 unsigned int*)(Abase + gsrc0 + ((size_t)(j * 64) << 12) + ((T & 63) << 6)),
        (AS3 unsigned int*)(sm + ((T & 1) << 14) + j * 4096 + dst0), 16, 0, 0);
  };
  auto stB = [&](int T, int j) {
    __builtin_amdgcn_global_load_lds(
        (const AS1 unsigned int*)(Bbase + gsrc0 + ((size_t)(j * 64) << 12) + ((T & 63) << 6)),
        (AS3 unsigned int*)(sm + 32768 + ((T & 1) << 14) + j * 4096 + dst0), 16, 0, 0);
  };

  const int baseAh = (wr * 128 + lrow) * 64 + ((kg ^ sw) << 3);
  const int baseAl = (wr * 128 + lrow) * 64 + (((4 | kg) ^ sw) << 3);
  const int baseBh = (wc * 64 + lrow) * 64 + ((kg ^ sw) << 3);
  const int baseBl = (wc * 64 + lrow) * 64 + (((4 | kg) ^ sw) << 3);

  f32x4 acc[8][4] = {};
  bf16x8 bh[4], bl[4];

  // prologue: T0 full (8), then B(T1) j0-3 + A(T1) j0,j2 (6) -> vmcnt(6)=T0 landed
  stA(0, 0); stA(0, 1); stA(0, 2); stA(0, 3);
  stB(0, 0); stB(0, 1); stB(0, 2); stB(0, 3);
  stB(1, 0); stB(1, 1); stB(1, 2); stB(1, 3);
  stA(1, 0); stA(1, 2);
  asm volatile("s_waitcnt vmcnt(6)" ::: "memory");
  __builtin_amdgcn_sched_barrier(0);
  __builtin_amdgcn_s_barrier();

  for (int i = 0; i < 32; ++i) {
    const int t0 = 2 * i;
#pragma unroll
    for (int p = 0; p < 8; ++p) {
      const int q = p & 3;
      const int t = t0 + (p >> 2);
      const u16* la = sm + ((t & 1) << 14);
      const u16* lb = sm + 32768 + ((t & 1) << 14);
      if (q == 0) {
#pragma unroll
        for (int n = 0; n < 4; ++n) {
          bh[n] = *(const bf16x8*)&lb[baseBh + n * 1024];
          bl[n] = *(const bf16x8*)&lb[baseBl + n * 1024];
        }
      }
      bf16x8 ah0 = *(const bf16x8*)&la[baseAh + (2 * q) * 1024];
      bf16x8 al0 = *(const bf16x8*)&la[baseAl + (2 * q) * 1024];
      bf16x8 ah1 = *(const bf16x8*)&la[baseAh + (2 * q + 1) * 1024];
      bf16x8 al1 = *(const bf16x8*)&la[baseAl + (2 * q + 1) * 1024];
      switch (p) {
        case 0: stA(t0 + 1, 1); stA(t0 + 1, 3); break;
        case 1: stB(t0 + 2, 0); stB(t0 + 2, 1); break;
        case 2: stB(t0 + 2, 2); stB(t0 + 2, 3); break;
        case 3: stA(t0 + 2, 0); stA(t0 + 2, 2); break;
        case 4: stA(t0 + 2, 1); stA(t0 + 2, 3); break;
        case 5: stB(t0 + 3, 0); stB(t0 + 3, 1); break;
        case 6: stB(t0 + 3, 2); stB(t0 + 3, 3); break;
        case 7: stA(t0 + 3, 0); stA(t0 + 3, 2); break;
      }
      __builtin_amdgcn_s_barrier();
      __builtin_amdgcn_s_setprio(1);
      const int m0 = 2 * q, m1 = 2 * q + 1;
#pragma unroll
      for (int n = 0; n < 4; ++n) { MF(acc[m0][n], ah0, bh[n]); MF(acc[m1][n], ah1, bh[n]); }
#pragma unroll
      for (int n = 0; n < 4; ++n) { MF(acc[m0][n], ah0, bl[n]); MF(acc[m1][n], ah1, bl[n]); }
#pragma unroll
      for (int n = 0; n < 4; ++n) { MF(acc[m0][n], al0, bh[n]); MF(acc[m1][n], al1, bh[n]); }
      __builtin_amdgcn_s_setprio(0);
      asm volatile("s_waitcnt lgkmcnt(0)" ::: "memory");
      __builtin_amdgcn_sched_barrier(0);
      if (q == 3) {
        asm volatile("s_waitcnt vmcnt(6)" ::: "memory");
        __builtin_amdgcn_sched_barrier(0);
      }
      __builtin_amdgcn_s_barrier();
    }
  }
  asm volatile("s_waitcnt vmcnt(0)" ::: "memory");

  // epilogue: C frag col=lane&15, row=kg*4+j
#pragma unroll
  for (int m = 0; m < 8; ++m) {
#pragma unroll
    for (int n = 0; n < 4; ++n) {
#pragma unroll
      for (int j = 0; j < 4; ++j) {
        int gr = row0 + wr * 128 + m * 16 + kg * 4 + j;
        int gc = col0 + wc * 64 + n * 16 + lrow;
        Cout[((size_t)gr << 12) + gc] = acc[m][n][j];
      }
    }
  }
}

// ---- row softmax in place over [4096][4096] f32
__global__ __launch_bounds__(256) void k_softmax_rows(float* __restrict__ A) {
  const int row = blockIdx.x;
  float* p = A + ((size_t)row << 12);
  const int tid = threadIdx.x;
  const int lane = tid & 63, w = tid >> 6;
  float4 v[4];
  float mx = -3.0e38f;
#pragma unroll
  for (int i = 0; i < 4; ++i) {
    v[i] = ((const float4*)p)[tid + (i << 8)];
    mx = fmaxf(mx, fmaxf(fmaxf(v[i].x, v[i].y), fmaxf(v[i].z, v[i].w)));
  }
#pragma unroll
  for (int off = 32; off; off >>= 1) mx = fmaxf(mx, __shfl_xor(mx, off, 64));
  __shared__ float redm[4], reds[4];
  if (lane == 0) redm[w] = mx;
  __syncthreads();
  mx = fmaxf(fmaxf(redm[0], redm[1]), fmaxf(redm[2], redm[3]));
  float s = 0.f;
#pragma unroll
  for (int i = 0; i < 4; ++i) {
    v[i].x = __expf(v[i].x - mx);
    v[i].y = __expf(v[i].y - mx);
    v[i].z = __expf(v[i].z - mx);
    v[i].w = __expf(v[i].w - mx);
    s += (v[i].x + v[i].y) + (v[i].z + v[i].w);
  }
#pragma unroll
  for (int off = 32; off; off >>= 1) s += __shfl_xor(s, off, 64);
  if (lane == 0) reds[w] = s;
  __syncthreads();
  s = (reds[0] + reds[1]) + (reds[2] + reds[3]);
  const float inv = 1.0f / s;
#pragma unroll
  for (int i = 0; i < 4; ++i) {
    v[i].x *= inv; v[i].y *= inv; v[i].z *= inv; v[i].w *= inv;
    ((float4*)p)[tid + (i << 8)] = v[i];
  }
}

extern "C" void kernel_launch(void* const* d_in, const int* in_sizes, int n_in,
                              void* d_out, int out_size, void* d_ws, size_t ws_size,
                              hipStream_t stream) {
  (void)in_sizes; (void)n_in; (void)out_size; (void)ws_size;
  const float* Ws = (const float*)d_in[0];   // [4096][2048] f32
  const float* W  = (const float*)d_in[1];   // [1][2048][2048] f32
  // d_in[2] = bias[1]: constant across each row -> softmax-invariant, skipped.
  float* out = (float*)d_out;                // [4096][4096] f32

  u16* ws_pack = (u16*)d_ws;                       // [4096][4096] u16
  u16* wt_pack = ws_pack + (size_t)4096 * 4096;    // [2048][4096] u16
  u16* t_pack  = wt_pack + (size_t)2048 * 4096;    // [4096][4096] u16

  // fused prep: Ws-pack + W-transpose-pack in one launch
  k_prep<<<8192, 256, 0, stream>>>(Ws, ws_pack, W, wt_pack);
  // t = Ws @ W  (NT), split-epilogue back into packed hi/lo
  k_gemm_nt<<<512, 256, 0, stream>>>(ws_pack, wt_pack, t_pack);
  // A = t @ Ws^T (NT), round-8 8-phase 256^2 + XCD swizzle, fp32 logits
  k_gemm256<<<256, 512, 0, stream>>>(t_pack, ws_pack, out);
  k_softmax_rows<<<4096, 256, 0, stream>>>(out);
}